// Round 15
// baseline (320.163 us; speedup 1.0000x reference)
//
#include <hip/hip_runtime.h>
#include <hip/hip_bf16.h>

// HypLoRA: out = x@W^T + b + 2 * scale2(row) * (u(row) @ B)
//   u(row)    = s1 * (x_row @ A), s1 = min(||x||,1.5)/max(||x||,EPS)
//   scale2    = min(n2,1.5)/max(n2,EPS),  n2^2 = u^T (B B^T) u
// K = clip(exp(log_K),...) cancels identically in log(exp(.)) at origin.
//
// Launch 1 (k_prep): G | 4-rows-per-block x-pass (A reuse x4) | W->bf16.
// Launch 2 (k_gemm): round-14 skeleton (8-phase, frag-pipelined, MFMA-first
//   pin, vmcnt(6) at P4/P8) with MFMA shape switched 16x16x32 -> 32x32x16:
//   ~15-20% faster matrix pipe (m06 2075 TF vs m119 2495 TF), half the
//   instruction count, same LDS read volume. A/B operand: row=lane&31,
//   k-chunk=(lane>>5)*8. C/D (m74/m101-verified): col=lane&31,
//   row=(reg&3)+8*(reg>>2)+4*(lane>>5).
// Round-7 lesson: forcing 4 waves/SIMD spills acc (7.5GB scratch). Keep (512,2).
// Round-8 lesson: lane-consecutive d mandatory in the A gather.
// Rounds 6-14 lesson: window structure is at its floor; LDS+MFMA additive.

#define DD 4096
#define MR 8192
#define BM 256
#define BN 256
#define BK 64

typedef float f32x4 __attribute__((ext_vector_type(4)));
typedef float f32x16 __attribute__((ext_vector_type(16)));
typedef __bf16 bf16x8 __attribute__((ext_vector_type(8)));

#define GLOAD_LDS16(gptr, lptr)                                                        \
  __builtin_amdgcn_global_load_lds((const __attribute__((address_space(1))) void*)(gptr), \
                                   (__attribute__((address_space(3))) void*)(lptr), 16, 0, 0)

__device__ __forceinline__ __bf16 f2bf(float f) { return (__bf16)f; }

// ---------------- fused prep (round-10, proven) ----------------
__global__ __launch_bounds__(256) void k_prep(const float* __restrict__ x,
                                              const float* __restrict__ W,
                                              const float* __restrict__ A,
                                              const float* __restrict__ Bm,
                                              __bf16* __restrict__ Xb,
                                              __bf16* __restrict__ Wb,
                                              float* __restrict__ U,
                                              float* __restrict__ G) {
  int bid = blockIdx.x;
  int t = threadIdx.x;
  int lane = t & 63, wid = t >> 6;

  if (bid == 0) {
    float g[64];
#pragma unroll
    for (int i = 0; i < 64; ++i) g[i] = 0.f;
    for (int d = t; d < DD; d += 256) {
      float br[8];
#pragma unroll
      for (int r = 0; r < 8; ++r) br[r] = Bm[r * DD + d];
#pragma unroll
      for (int r = 0; r < 8; ++r)
#pragma unroll
        for (int s = 0; s < 8; ++s) g[r * 8 + s] += br[r] * br[s];
    }
    __shared__ float gs[4][64];
#pragma unroll
    for (int i = 0; i < 64; ++i) {
      float v = g[i];
      for (int off = 32; off >= 1; off >>= 1) v += __shfl_down(v, off, 64);
      if (lane == 0) gs[wid][i] = v;
    }
    __syncthreads();
    if (t < 64) G[t] = gs[0][t] + gs[1][t] + gs[2][t] + gs[3][t];
  } else if (bid <= 2048) {
    int r0 = (bid - 1) * 4;
    const float* xr0 = x + (size_t)r0 * DD;
    __bf16* xb0 = Xb + (size_t)r0 * DD;
    float nsq[4] = {0.f, 0.f, 0.f, 0.f};
    float p[4][8] = {};
#pragma unroll
    for (int i = 0; i < 16; ++i) {
      int d = t + 256 * i;
      f32x4 a0 = *reinterpret_cast<const f32x4*>(A + (size_t)d * 8);
      f32x4 a1 = *reinterpret_cast<const f32x4*>(A + (size_t)d * 8 + 4);
#pragma unroll
      for (int r = 0; r < 4; ++r) {
        float xv = xr0[(size_t)r * DD + d];
        xb0[(size_t)r * DD + d] = f2bf(xv);
        nsq[r] += xv * xv;
        p[r][0] += xv * a0[0]; p[r][1] += xv * a0[1];
        p[r][2] += xv * a0[2]; p[r][3] += xv * a0[3];
        p[r][4] += xv * a1[0]; p[r][5] += xv * a1[1];
        p[r][6] += xv * a1[2]; p[r][7] += xv * a1[3];
      }
    }
    for (int off = 32; off >= 1; off >>= 1) {
#pragma unroll
      for (int r = 0; r < 4; ++r) {
        nsq[r] += __shfl_down(nsq[r], off, 64);
#pragma unroll
        for (int q = 0; q < 8; ++q) p[r][q] += __shfl_down(p[r][q], off, 64);
      }
    }
    __shared__ float red[4][36];
    if (lane == 0) {
#pragma unroll
      for (int r = 0; r < 4; ++r) {
        red[wid][r * 9] = nsq[r];
#pragma unroll
        for (int q = 0; q < 8; ++q) red[wid][r * 9 + 1 + q] = p[r][q];
      }
    }
    __syncthreads();
    if (t < 4) {
      float ns = red[0][t * 9] + red[1][t * 9] + red[2][t * 9] + red[3][t * 9];
      float u[8];
#pragma unroll
      for (int q = 0; q < 8; ++q)
        u[q] = red[0][t * 9 + 1 + q] + red[1][t * 9 + 1 + q] +
               red[2][t * 9 + 1 + q] + red[3][t * 9 + 1 + q];
      float n = sqrtf(ns);
      float s1 = fminf(n, 1.5f) / fmaxf(n, 1e-7f);
#pragma unroll
      for (int q = 0; q < 8; ++q) U[(size_t)(r0 + t) * 8 + q] = s1 * u[q];
    }
  } else {
    int i = (bid - 2049) * 256 + t;
    const f32x4* s = reinterpret_cast<const f32x4*>(W) + (size_t)i * 2;
    f32x4 v0 = s[0], v1 = s[1];
    bf16x8 o;
    o[0] = f2bf(v0[0]); o[1] = f2bf(v0[1]); o[2] = f2bf(v0[2]); o[3] = f2bf(v0[3]);
    o[4] = f2bf(v1[0]); o[5] = f2bf(v1[1]); o[6] = f2bf(v1[2]); o[7] = f2bf(v1[3]);
    reinterpret_cast<bf16x8*>(Wb)[i] = o;
  }
}

// ---------------- main GEMM: out = Xb@Wb^T + bias + c @ B ----------------
// LDS per 64KB buf: B.k0@0, A.k0@16K, B.k1@32K, A.k1@48K; buf1 @+64K.
// Regions [256][32] bf16, slot swizzle phys = logical ^ ((row>>1)&3);
// source k-offset inverse-swizzled j=(t&3)^((t>>3)&3) (unchanged staging).
// 32x32x16 MFMA: wave tile 128x64 = 4(fm) x 2(fn) frags of 32x32; per region
// (32 k) 2 k-subtiles of 16. Lane: row/col = lane&31, k-chunk = (lane>>5)*8.
// Read slot = (ksub*2 + (lane>>5)) ^ (((lane&31)>>1)&3) — covers all 32
// banks per 8-row group (checked). Window k: { STAGE; BAR; MMQ (frags from
// window k-1); next-window LDA/LDB; PIN(MFMA8 -> DSREADn); BAR }. VM6 at
// P4/P8 precedes buf-switch reads (hazards identical to round-14).
__global__ __launch_bounds__(512, 2) void k_gemm(const __bf16* __restrict__ Xb,
                                                 const __bf16* __restrict__ Wb,
                                                 const float* __restrict__ bias,
                                                 const float* __restrict__ U,
                                                 const float* __restrict__ G,
                                                 const float* __restrict__ Bm,
                                                 float* __restrict__ out) {
  __shared__ union {
    char raw[131072];
    struct { float cs[256][8]; float bs2[8][256]; } epi;
  } sm;
  char* smc = sm.raw;

  const int nwg = (MR / BM) * (DD / BN);  // 512, %8==0 -> bijective swizzle
  int wg = ((int)blockIdx.x % 8) * (nwg / 8) + (int)blockIdx.x / 8;
  int tm = wg / (DD / BN);
  int tn = wg % (DD / BN);
  int row0 = tm * BM, col0 = tn * BN;

  int t = threadIdx.x;
  int lane = t & 63, wid = t >> 6;
  int wm = wid >> 2, wn = wid & 3;  // 2x4 waves, each owns 128x64 of C
  int l31 = lane & 31;
  int hi2 = lane >> 5;              // k-chunk select (0..1)
  int sw2 = (l31 >> 1) & 3;         // read-side swizzle key (row base %32==0)

  f32x16 acc[4][2] = {};            // 4 fm x 2 fn frags of 32x32
  bf16x8 aA[4], aB[4], bA[4], bB[4];  // [frag*2 + ksub]

  auto STAGE = [&](const __bf16* mat, int rowbase, int tau, int ks, int ldsOff) {
    int j = (t & 3) ^ ((t >> 3) & 3);
    int kk = ((tau & 63) << 6) + (ks << 5) + (j << 3);
    const __bf16* src = mat + (size_t)(rowbase + (t >> 2)) * DD + kk;
    char* dst = smc + ldsOff + t * 16;
    GLOAD_LDS16(src, dst);
    GLOAD_LDS16(src + (size_t)128 * DD, dst + 8192);
  };

// dst[fm2*2+ksub] : A frag rows wm*128 + (mbase+fm2)*32 + l31, region ks
#define LDA32(dst, buf, ks, mbase)                                              \
  _Pragma("unroll") for (int fm2 = 0; fm2 < 2; ++fm2)                           \
  _Pragma("unroll") for (int ksub = 0; ksub < 2; ++ksub)                        \
      dst[fm2 * 2 + ksub] = *reinterpret_cast<const bf16x8*>(                   \
          smc + (buf)*65536 + 16384 + (ks)*32768 +                              \
          (wm * 128 + ((mbase) + fm2) * 32 + l31) * 64 +                        \
          (((ksub * 2 + hi2) ^ sw2) << 4));
#define LDB32(dst, buf, ks)                                                     \
  _Pragma("unroll") for (int fn = 0; fn < 2; ++fn)                              \
  _Pragma("unroll") for (int ksub = 0; ksub < 2; ++ksub)                        \
      dst[fn * 2 + ksub] = *reinterpret_cast<const bf16x8*>(                    \
          smc + (buf)*65536 + (ks)*32768 +                                      \
          (wn * 64 + fn * 32 + l31) * 64 +                                      \
          (((ksub * 2 + hi2) ^ sw2) << 4));
#define MMQ32(aset, bset, mbase)                                                \
  __builtin_amdgcn_s_setprio(1);                                                \
  _Pragma("unroll") for (int fm2 = 0; fm2 < 2; ++fm2)                           \
  _Pragma("unroll") for (int fn = 0; fn < 2; ++fn)                              \
  _Pragma("unroll") for (int ksub = 0; ksub < 2; ++ksub)                        \
      acc[(mbase) + fm2][fn] = __builtin_amdgcn_mfma_f32_32x32x16_bf16(         \
          aset[fm2 * 2 + ksub], bset[fn * 2 + ksub], acc[(mbase) + fm2][fn],    \
          0, 0, 0);                                                             \
  __builtin_amdgcn_s_setprio(0);
#define BAR() __builtin_amdgcn_s_barrier()
#define VM6() asm volatile("s_waitcnt vmcnt(6)" ::: "memory")
// Pin: 8-MFMA cluster FIRST, then next-window ds_reads (drain under MFMA).
#define PIN(nreads)                                          \
  __builtin_amdgcn_sched_group_barrier(0x8, 8, 0);           \
  __builtin_amdgcn_sched_group_barrier(0x100, (nreads), 0)

  // -------- prologue: tile0 all 4 regions, tile1 first 3 --------
  STAGE(Wb, col0, 0, 0, 0);
  STAGE(Xb, row0, 0, 0, 16384);
  STAGE(Wb, col0, 0, 1, 32768);
  STAGE(Xb, row0, 0, 1, 49152);
  asm volatile("s_waitcnt vmcnt(4)" ::: "memory");
  STAGE(Wb, col0, 1, 0, 65536 + 0);
  STAGE(Xb, row0, 1, 0, 65536 + 16384);
  STAGE(Wb, col0, 1, 1, 65536 + 32768);
  VM6();  // tile0 fully landed
  BAR();
  // preload window-1 fragments (buf0, region k0)
  LDA32(aA, 0, 0, 0);
  LDB32(bA, 0, 0);

  for (int i = 0; i < DD / BK / 2; ++i) {
    int T = 2 * i;
    // P1: MMQ(aA,bA,0) ; read fm2-3 k0 ; stage X(T+1,k1)->buf1.A1
    STAGE(Xb, row0, T + 1, 1, 65536 + 49152);
    BAR();
    MMQ32(aA, bA, 0);
    LDA32(aB, 0, 0, 2);
    PIN(4);
    BAR();
    // P2: MMQ(aB,bA,2) ; read fm0-1 k1 + B k1 ; stage W(T+2,k0)->buf0.B0
    STAGE(Wb, col0, T + 2, 0, 0);
    BAR();
    MMQ32(aB, bA, 2);
    LDA32(aA, 0, 1, 0);
    LDB32(bB, 0, 1);
    PIN(8);
    BAR();
    // P3: MMQ(aA,bB,0) ; read fm2-3 k1 ; stage X(T+2,k0)->buf0.A0
    STAGE(Xb, row0, T + 2, 0, 16384);
    BAR();
    MMQ32(aA, bB, 0);
    LDA32(aB, 0, 1, 2);
    PIN(4);
    BAR();
    // P4: MMQ(aB,bB,2) ; VM6 ; read buf1 k0 (tile T+1 landed)
    STAGE(Wb, col0, T + 2, 1, 32768);
    BAR();
    MMQ32(aB, bB, 2);
    VM6();
    LDA32(aA, 1, 0, 0);
    LDB32(bA, 1, 0);
    PIN(8);
    BAR();
    // P5: MMQ(aA,bA,0) ; read fm2-3 k0 ; stage X(T+2,k1)->buf0.A1
    STAGE(Xb, row0, T + 2, 1, 49152);
    BAR();
    MMQ32(aA, bA, 0);
    LDA32(aB, 1, 0, 2);
    PIN(4);
    BAR();
    // P6: MMQ(aB,bA,2) ; read fm0-1 k1 + B k1 ; stage W(T+3,k0)->buf1.B0
    STAGE(Wb, col0, T + 3, 0, 65536 + 0);
    BAR();
    MMQ32(aB, bA, 2);
    LDA32(aA, 1, 1, 0);
    LDB32(bB, 1, 1);
    PIN(8);
    BAR();
    // P7: MMQ(aA,bB,0) ; read fm2-3 k1 ; stage X(T+3,k0)->buf1.A0
    STAGE(Xb, row0, T + 3, 0, 65536 + 16384);
    BAR();
    MMQ32(aA, bB, 0);
    LDA32(aB, 1, 1, 2);
    PIN(4);
    BAR();
    // P8: MMQ(aB,bB,2) ; VM6 ; read next buf0 k0 (tile T+2 landed)
    STAGE(Wb, col0, T + 3, 1, 65536 + 32768);
    BAR();
    MMQ32(aB, bB, 2);
    VM6();
    LDA32(aA, 0, 0, 0);
    LDB32(bA, 0, 0);
    PIN(8);
    BAR();
  }

  // -------- epilogue: drain DMA, compute c from U,G; stage B slice --------
  asm volatile("s_waitcnt vmcnt(0)" ::: "memory");
  __syncthreads();
  {
    int rr = t >> 6, cc = (t & 63) * 4;
    *reinterpret_cast<f32x4*>(&sm.epi.bs2[rr][cc]) =
        *reinterpret_cast<const f32x4*>(Bm + (size_t)rr * DD + col0 + cc);
  }
  if (t < 256) {
    f32x4 u0 = *reinterpret_cast<const f32x4*>(U + (size_t)(row0 + t) * 8);
    f32x4 u1 = *reinterpret_cast<const f32x4*>(U + (size_t)(row0 + t) * 8 + 4);
    float u[8] = {u0[0], u0[1], u0[2], u0[3], u1[0], u1[1], u1[2], u1[3]};
    float n2sq = 0.f;
#pragma unroll
    for (int r = 0; r < 8; ++r) {
      float s = 0.f;
#pragma unroll
      for (int q = 0; q < 8; ++q) s += G[r * 8 + q] * u[q];
      n2sq += u[r] * s;
    }
    float n2 = sqrtf(fmaxf(n2sq, 0.f));
    float sc2 = 2.0f * fminf(n2, 1.5f) / fmaxf(n2, 1e-7f);
#pragma unroll
    for (int r = 0; r < 8; ++r) sm.epi.cs[t][r] = sc2 * u[r];
  }
  __syncthreads();

  // C/D layout (verified m74/m101): col = lane&31, row = (r&3)+8*(r>>2)+4*hi2
  float biasv[2], bcol[2][8];
#pragma unroll
  for (int fn = 0; fn < 2; ++fn) {
    int oc = wn * 64 + fn * 32 + l31;
    biasv[fn] = bias[col0 + oc];
#pragma unroll
    for (int q = 0; q < 8; ++q) bcol[fn][q] = sm.epi.bs2[q][oc];
  }
#pragma unroll
  for (int fm = 0; fm < 4; ++fm) {
#pragma unroll
    for (int r = 0; r < 16; ++r) {
      int rl = wm * 128 + fm * 32 + (r & 3) + 8 * (r >> 2) + 4 * hi2;
      float c0 = sm.epi.cs[rl][0], c1 = sm.epi.cs[rl][1], c2 = sm.epi.cs[rl][2],
            c3 = sm.epi.cs[rl][3], c4 = sm.epi.cs[rl][4], c5 = sm.epi.cs[rl][5],
            c6 = sm.epi.cs[rl][6], c7 = sm.epi.cs[rl][7];
      float* orow = out + (size_t)(row0 + rl) * DD + col0 + wn * 64 + l31;
#pragma unroll
      for (int fn = 0; fn < 2; ++fn) {
        float delta = c0 * bcol[fn][0] + c1 * bcol[fn][1] + c2 * bcol[fn][2] +
                      c3 * bcol[fn][3] + c4 * bcol[fn][4] + c5 * bcol[fn][5] +
                      c6 * bcol[fn][6] + c7 * bcol[fn][7];
        orow[fn * 32] = acc[fm][fn][r] + biasv[fn] + delta;
      }
    }
  }
}

extern "C" void kernel_launch(void* const* d_in, const int* in_sizes, int n_in,
                              void* d_out, int out_size, void* d_ws, size_t ws_size,
                              hipStream_t stream) {
  const float* x = (const float*)d_in[0];   // [4,2048,4096]
  const float* W = (const float*)d_in[1];   // [4096,4096]
  const float* b = (const float*)d_in[2];   // [4096]
  const float* A = (const float*)d_in[3];   // [4096,8]
  const float* Bm = (const float*)d_in[4];  // [8,4096]
  // d_in[5] = log_K : K cancels analytically, unused.
  float* out = (float*)d_out;

  char* ws = (char*)d_ws;
  __bf16* Xb = (__bf16*)ws;                                    // 64 MB
  __bf16* Wb = (__bf16*)(ws + (size_t)64 * 1024 * 1024);       // 32 MB
  float* U = (float*)(ws + (size_t)96 * 1024 * 1024);          // 256 KB
  float* G = (float*)(ws + (size_t)96 * 1024 * 1024 + 256 * 1024);

  k_prep<<<1 + 2048 + 8192, 256, 0, stream>>>(x, W, A, Bm, Xb, Wb, U, G);
  k_gemm<<<(MR / BM) * (DD / BN), 512, 0, stream>>>(Xb, Wb, b, U, G, Bm, out);
}

// Round 16
// 303.197 us; speedup vs baseline: 1.0560x; 1.0560x over previous
//
#include <hip/hip_runtime.h>
#include <hip/hip_bf16.h>

// HypLoRA: out = x@W^T + b + 2 * scale2(row) * (u(row) @ B)
//   u(row)    = s1 * (x_row @ A), s1 = min(||x||,1.5)/max(||x||,EPS)
//   scale2    = min(n2,1.5)/max(n2,EPS),  n2^2 = u^T (B B^T) u
// K = clip(exp(log_K),...) cancels identically in log(exp(.)) at origin.
//
// FINAL CONFIG (= round-14 champion, 306 µs):
// Launch 1 (k_prep): G | 4-rows-per-block x-pass (A reuse x4) | W->bf16.
// Launch 2 (k_gemm): 256x256, BK=64, 2x64KB LDS dbuf, slot swizzle, 8-phase
//   frag-pipelined schedule, MFMA-first sched_group_barrier pin, vmcnt(6)
//   at P4/P8, setprio around MFMA.
// Lessons ledger:
//  r7:  launch_bounds(512,4) spills acc -> 7.5GB scratch. Keep (512,2).
//  r8:  lane-consecutive d mandatory in the A gather; addr VALU not critical.
//  r11: window merge (fewer barriers) regresses; cost scales with window len.
//  r13: removing mid-tile barriers de-syncs waves, -30%.
//  r15: 32x32x16 MFMA: +10x bank conflicts (2.4e6->2.6e7), GEMM 239->254us.
//  Cycle model: per K-tile ~2483 cyc MFMA + ~2000 cyc LDS (both at measured
//  ceilings), ~additive in this barrier template; r14 pin = best (+2%).

#define DD 4096
#define MR 8192
#define BM 256
#define BN 256
#define BK 64

typedef float f32x4 __attribute__((ext_vector_type(4)));
typedef __bf16 bf16x8 __attribute__((ext_vector_type(8)));

#define GLOAD_LDS16(gptr, lptr)                                                        \
  __builtin_amdgcn_global_load_lds((const __attribute__((address_space(1))) void*)(gptr), \
                                   (__attribute__((address_space(3))) void*)(lptr), 16, 0, 0)

__device__ __forceinline__ __bf16 f2bf(float f) { return (__bf16)f; }

// ---------------- fused prep (round-10, proven) ----------------
__global__ __launch_bounds__(256) void k_prep(const float* __restrict__ x,
                                              const float* __restrict__ W,
                                              const float* __restrict__ A,
                                              const float* __restrict__ Bm,
                                              __bf16* __restrict__ Xb,
                                              __bf16* __restrict__ Wb,
                                              float* __restrict__ U,
                                              float* __restrict__ G) {
  int bid = blockIdx.x;
  int t = threadIdx.x;
  int lane = t & 63, wid = t >> 6;

  if (bid == 0) {
    float g[64];
#pragma unroll
    for (int i = 0; i < 64; ++i) g[i] = 0.f;
    for (int d = t; d < DD; d += 256) {
      float br[8];
#pragma unroll
      for (int r = 0; r < 8; ++r) br[r] = Bm[r * DD + d];
#pragma unroll
      for (int r = 0; r < 8; ++r)
#pragma unroll
        for (int s = 0; s < 8; ++s) g[r * 8 + s] += br[r] * br[s];
    }
    __shared__ float gs[4][64];
#pragma unroll
    for (int i = 0; i < 64; ++i) {
      float v = g[i];
      for (int off = 32; off >= 1; off >>= 1) v += __shfl_down(v, off, 64);
      if (lane == 0) gs[wid][i] = v;
    }
    __syncthreads();
    if (t < 64) G[t] = gs[0][t] + gs[1][t] + gs[2][t] + gs[3][t];
  } else if (bid <= 2048) {
    int r0 = (bid - 1) * 4;
    const float* xr0 = x + (size_t)r0 * DD;
    __bf16* xb0 = Xb + (size_t)r0 * DD;
    float nsq[4] = {0.f, 0.f, 0.f, 0.f};
    float p[4][8] = {};
#pragma unroll
    for (int i = 0; i < 16; ++i) {
      int d = t + 256 * i;
      f32x4 a0 = *reinterpret_cast<const f32x4*>(A + (size_t)d * 8);
      f32x4 a1 = *reinterpret_cast<const f32x4*>(A + (size_t)d * 8 + 4);
#pragma unroll
      for (int r = 0; r < 4; ++r) {
        float xv = xr0[(size_t)r * DD + d];
        xb0[(size_t)r * DD + d] = f2bf(xv);
        nsq[r] += xv * xv;
        p[r][0] += xv * a0[0]; p[r][1] += xv * a0[1];
        p[r][2] += xv * a0[2]; p[r][3] += xv * a0[3];
        p[r][4] += xv * a1[0]; p[r][5] += xv * a1[1];
        p[r][6] += xv * a1[2]; p[r][7] += xv * a1[3];
      }
    }
    for (int off = 32; off >= 1; off >>= 1) {
#pragma unroll
      for (int r = 0; r < 4; ++r) {
        nsq[r] += __shfl_down(nsq[r], off, 64);
#pragma unroll
        for (int q = 0; q < 8; ++q) p[r][q] += __shfl_down(p[r][q], off, 64);
      }
    }
    __shared__ float red[4][36];
    if (lane == 0) {
#pragma unroll
      for (int r = 0; r < 4; ++r) {
        red[wid][r * 9] = nsq[r];
#pragma unroll
        for (int q = 0; q < 8; ++q) red[wid][r * 9 + 1 + q] = p[r][q];
      }
    }
    __syncthreads();
    if (t < 4) {
      float ns = red[0][t * 9] + red[1][t * 9] + red[2][t * 9] + red[3][t * 9];
      float u[8];
#pragma unroll
      for (int q = 0; q < 8; ++q)
        u[q] = red[0][t * 9 + 1 + q] + red[1][t * 9 + 1 + q] +
               red[2][t * 9 + 1 + q] + red[3][t * 9 + 1 + q];
      float n = sqrtf(ns);
      float s1 = fminf(n, 1.5f) / fmaxf(n, 1e-7f);
#pragma unroll
      for (int q = 0; q < 8; ++q) U[(size_t)(r0 + t) * 8 + q] = s1 * u[q];
    }
  } else {
    int i = (bid - 2049) * 256 + t;
    const f32x4* s = reinterpret_cast<const f32x4*>(W) + (size_t)i * 2;
    f32x4 v0 = s[0], v1 = s[1];
    bf16x8 o;
    o[0] = f2bf(v0[0]); o[1] = f2bf(v0[1]); o[2] = f2bf(v0[2]); o[3] = f2bf(v0[3]);
    o[4] = f2bf(v1[0]); o[5] = f2bf(v1[1]); o[6] = f2bf(v1[2]); o[7] = f2bf(v1[3]);
    reinterpret_cast<bf16x8*>(Wb)[i] = o;
  }
}

// ---------------- main GEMM: out = Xb@Wb^T + bias + c @ B ----------------
// LDS per 64KB buf: B.k0@0, A.k0@16K, B.k1@32K, A.k1@48K; buf1 @+64K.
// Regions [256][32] bf16, slot swizzle phys = logical ^ ((row>>1)&3);
// source k-offset inverse-swizzled j=(t&3)^((t>>3)&3).
// Window k: { STAGE; BAR; MMQ (frags read in window k-1); LDA/LDB for window
// k+1; PIN(MFMA16 -> DSREADn); BAR }. VM6 at P4/P8 precedes the buf-switch
// reads (per-wave retire count, hazard-verified rounds 5/6/14).
__global__ __launch_bounds__(512, 2) void k_gemm(const __bf16* __restrict__ Xb,
                                                 const __bf16* __restrict__ Wb,
                                                 const float* __restrict__ bias,
                                                 const float* __restrict__ U,
                                                 const float* __restrict__ G,
                                                 const float* __restrict__ Bm,
                                                 float* __restrict__ out) {
  __shared__ union {
    char raw[131072];
    struct { float cs[256][8]; float bs2[8][256]; } epi;
  } sm;
  char* smc = sm.raw;

  const int nwg = (MR / BM) * (DD / BN);  // 512, %8==0 -> bijective swizzle
  int wg = ((int)blockIdx.x % 8) * (nwg / 8) + (int)blockIdx.x / 8;
  int tm = wg / (DD / BN);
  int tn = wg % (DD / BN);
  int row0 = tm * BM, col0 = tn * BN;

  int t = threadIdx.x;
  int lane = t & 63, wid = t >> 6;
  int wm = wid >> 2, wn = wid & 3;  // 2x4 waves, each owns 128x64 of C
  int fr = lane & 15;
  int hi = lane >> 4;
  int sw = (fr >> 1) & 3;

  f32x4 acc[8][4] = {};
  bf16x8 aA[4], aB[4], bA[4], bB[4];

  auto STAGE = [&](const __bf16* mat, int rowbase, int tau, int ks, int ldsOff) {
    int j = (t & 3) ^ ((t >> 3) & 3);
    int kk = ((tau & 63) << 6) + (ks << 5) + (j << 3);
    const __bf16* src = mat + (size_t)(rowbase + (t >> 2)) * DD + kk;
    char* dst = smc + ldsOff + t * 16;
    GLOAD_LDS16(src, dst);
    GLOAD_LDS16(src + (size_t)128 * DD, dst + 8192);
  };

#define LDA(dst, buf, ks, mbase)                                                \
  _Pragma("unroll") for (int j = 0; j < 4; ++j) dst[j] =                        \
      *reinterpret_cast<const bf16x8*>(smc + (buf)*65536 + 16384 + (ks)*32768 + \
                                       (wm * 128 + ((mbase) + j) * 16 + fr) * 64 + \
                                       ((hi ^ sw) << 4));
#define LDB(dst, buf, ks)                                                       \
  _Pragma("unroll") for (int j = 0; j < 4; ++j) dst[j] =                        \
      *reinterpret_cast<const bf16x8*>(smc + (buf)*65536 + (ks)*32768 +         \
                                       (wn * 64 + j * 16 + fr) * 64 +           \
                                       ((hi ^ sw) << 4));
#define MMQ(aset, bset, mbase)                                                  \
  __builtin_amdgcn_s_setprio(1);                                                \
  _Pragma("unroll") for (int j = 0; j < 4; ++j)                                 \
      _Pragma("unroll") for (int n = 0; n < 4; ++n)                             \
          acc[(mbase) + j][n] = __builtin_amdgcn_mfma_f32_16x16x32_bf16(        \
              aset[j], bset[n], acc[(mbase) + j][n], 0, 0, 0);                  \
  __builtin_amdgcn_s_setprio(0);
#define BAR() __builtin_amdgcn_s_barrier()
#define VM6() asm volatile("s_waitcnt vmcnt(6)" ::: "memory")
// Pin: MFMA cluster FIRST, then the next-window ds_reads (drain under MFMA).
#define PIN(nreads)                                          \
  __builtin_amdgcn_sched_group_barrier(0x8, 16, 0);          \
  __builtin_amdgcn_sched_group_barrier(0x100, (nreads), 0)

  // -------- prologue: tile0 all 4 regions, tile1 first 3 --------
  STAGE(Wb, col0, 0, 0, 0);
  STAGE(Xb, row0, 0, 0, 16384);
  STAGE(Wb, col0, 0, 1, 32768);
  STAGE(Xb, row0, 0, 1, 49152);
  asm volatile("s_waitcnt vmcnt(4)" ::: "memory");
  STAGE(Wb, col0, 1, 0, 65536 + 0);
  STAGE(Xb, row0, 1, 0, 65536 + 16384);
  STAGE(Wb, col0, 1, 1, 65536 + 32768);
  VM6();  // tile0 fully landed
  BAR();
  // preload window-1 fragments
  LDA(aA, 0, 0, 0);
  LDB(bA, 0, 0);

  for (int i = 0; i < DD / BK / 2; ++i) {
    int T = 2 * i;
    // P1: MMQ(aA,bA,0) ; read P2 frags ; stage X(T+1,k1)->buf1.A1
    STAGE(Xb, row0, T + 1, 1, 65536 + 49152);
    BAR();
    MMQ(aA, bA, 0);
    LDA(aB, 0, 0, 4);
    PIN(4);
    BAR();
    // P2: MMQ(aB,bA,4) ; read P3 frags ; stage W(T+2,k0)->buf0.B0
    STAGE(Wb, col0, T + 2, 0, 0);
    BAR();
    MMQ(aB, bA, 4);
    LDA(aA, 0, 1, 0);
    LDB(bB, 0, 1);
    PIN(8);
    BAR();
    // P3: MMQ(aA,bB,0) ; read P4 frags ; stage X(T+2,k0)->buf0.A0
    STAGE(Xb, row0, T + 2, 0, 16384);
    BAR();
    MMQ(aA, bB, 0);
    LDA(aB, 0, 1, 4);
    PIN(4);
    BAR();
    // P4: MMQ(aB,bB,4) ; VM6 ; read P5 frags from buf1 (tile T+1 landed)
    STAGE(Wb, col0, T + 2, 1, 32768);
    BAR();
    MMQ(aB, bB, 4);
    VM6();
    LDA(aA, 1, 0, 0);
    LDB(bA, 1, 0);
    PIN(8);
    BAR();
    // P5: MMQ(aA,bA,0) ; read P6 frags ; stage X(T+2,k1)->buf0.A1
    STAGE(Xb, row0, T + 2, 1, 49152);
    BAR();
    MMQ(aA, bA, 0);
    LDA(aB, 1, 0, 4);
    PIN(4);
    BAR();
    // P6: MMQ(aB,bA,4) ; read P7 frags ; stage W(T+3,k0)->buf1.B0
    STAGE(Wb, col0, T + 3, 0, 65536 + 0);
    BAR();
    MMQ(aB, bA, 4);
    LDA(aA, 1, 1, 0);
    LDB(bB, 1, 1);
    PIN(8);
    BAR();
    // P7: MMQ(aA,bB,0) ; read P8 frags ; stage X(T+3,k0)->buf1.A0
    STAGE(Xb, row0, T + 3, 0, 65536 + 16384);
    BAR();
    MMQ(aA, bB, 0);
    LDA(aB, 1, 1, 4);
    PIN(4);
    BAR();
    // P8: MMQ(aB,bB,4) ; VM6 ; read next-P1 frags from buf0 (tile T+2 landed)
    STAGE(Wb, col0, T + 3, 1, 65536 + 32768);
    BAR();
    MMQ(aB, bB, 4);
    VM6();
    LDA(aA, 0, 0, 0);
    LDB(bA, 0, 0);
    PIN(8);
    BAR();
  }

  // -------- epilogue: drain DMA, compute c from U,G; stage B slice --------
  asm volatile("s_waitcnt vmcnt(0)" ::: "memory");
  __syncthreads();
  {
    int rr = t >> 6, cc = (t & 63) * 4;
    *reinterpret_cast<f32x4*>(&sm.epi.bs2[rr][cc]) =
        *reinterpret_cast<const f32x4*>(Bm + (size_t)rr * DD + col0 + cc);
  }
  if (t < 256) {
    f32x4 u0 = *reinterpret_cast<const f32x4*>(U + (size_t)(row0 + t) * 8);
    f32x4 u1 = *reinterpret_cast<const f32x4*>(U + (size_t)(row0 + t) * 8 + 4);
    float u[8] = {u0[0], u0[1], u0[2], u0[3], u1[0], u1[1], u1[2], u1[3]};
    float n2sq = 0.f;
#pragma unroll
    for (int r = 0; r < 8; ++r) {
      float s = 0.f;
#pragma unroll
      for (int q = 0; q < 8; ++q) s += G[r * 8 + q] * u[q];
      n2sq += u[r] * s;
    }
    float n2 = sqrtf(fmaxf(n2sq, 0.f));
    float sc2 = 2.0f * fminf(n2, 1.5f) / fmaxf(n2, 1e-7f);
#pragma unroll
    for (int r = 0; r < 8; ++r) sm.epi.cs[t][r] = sc2 * u[r];
  }
  __syncthreads();

  int colb = col0 + wn * 64 + fr;
  float biasv[4], bcol[4][8];
#pragma unroll
  for (int n = 0; n < 4; ++n) {
    biasv[n] = bias[colb + n * 16];
#pragma unroll
    for (int r = 0; r < 8; ++r) bcol[n][r] = sm.epi.bs2[r][wn * 64 + fr + n * 16];
  }
#pragma unroll
  for (int m = 0; m < 8; ++m) {
#pragma unroll
    for (int j = 0; j < 4; ++j) {
      int rl = wm * 128 + m * 16 + hi * 4 + j;
      float c0 = sm.epi.cs[rl][0], c1 = sm.epi.cs[rl][1], c2 = sm.epi.cs[rl][2],
            c3 = sm.epi.cs[rl][3], c4 = sm.epi.cs[rl][4], c5 = sm.epi.cs[rl][5],
            c6 = sm.epi.cs[rl][6], c7 = sm.epi.cs[rl][7];
      float* orow = out + (size_t)(row0 + rl) * DD + colb;
#pragma unroll
      for (int n = 0; n < 4; ++n) {
        float delta = c0 * bcol[n][0] + c1 * bcol[n][1] + c2 * bcol[n][2] +
                      c3 * bcol[n][3] + c4 * bcol[n][4] + c5 * bcol[n][5] +
                      c6 * bcol[n][6] + c7 * bcol[n][7];
        orow[n * 16] = acc[m][n][j] + biasv[n] + delta;
      }
    }
  }
}

extern "C" void kernel_launch(void* const* d_in, const int* in_sizes, int n_in,
                              void* d_out, int out_size, void* d_ws, size_t ws_size,
                              hipStream_t stream) {
  const float* x = (const float*)d_in[0];   // [4,2048,4096]
  const float* W = (const float*)d_in[1];   // [4096,4096]
  const float* b = (const float*)d_in[2];   // [4096]
  const float* A = (const float*)d_in[3];   // [4096,8]
  const float* Bm = (const float*)d_in[4];  // [8,4096]
  // d_in[5] = log_K : K cancels analytically, unused.
  float* out = (float*)d_out;

  char* ws = (char*)d_ws;
  __bf16* Xb = (__bf16*)ws;                                    // 64 MB
  __bf16* Wb = (__bf16*)(ws + (size_t)64 * 1024 * 1024);       // 32 MB
  float* U = (float*)(ws + (size_t)96 * 1024 * 1024);          // 256 KB
  float* G = (float*)(ws + (size_t)96 * 1024 * 1024 + 256 * 1024);

  k_prep<<<1 + 2048 + 8192, 256, 0, stream>>>(x, W, A, Bm, Xb, Wb, U, G);
  k_gemm<<<(MR / BM) * (DD / BN), 512, 0, stream>>>(Xb, Wb, b, U, G, Bm, out);
}